// Round 1
// baseline (97.822 us; speedup 1.0000x reference)
//
#include <hip/hip_runtime.h>
#include <math.h>

#define OUT_NUM 1024
#define LUT_NUM 64
#define LUT_K   6
#define TBL     64      // 1 << LUT_K
#define BR_TOT  32      // 16 * 2
#define WSTRIDE 65      // pad 64 -> 65 floats: reg-load bank = (lut + i) % 32, 2-way (free)

__global__ __launch_bounds__(256, 4)
void lut_fwd_kernel(const float* __restrict__ x,
                    const float* __restrict__ w,
                    float* __restrict__ out)
{
    __shared__ float wq[LUT_NUM * WSTRIDE];   // 16.6 KiB

    const int o = blockIdx.x;       // output-feature index, 0..1023
    const int t = threadIdx.x;      // 0..255

    // ---- Phase 1: stage + soft-quantize w[o,:,:] (4096 floats) into LDS ----
    const float4* wrow4 = reinterpret_cast<const float4*>(w + (size_t)o * (LUT_NUM * TBL));
#pragma unroll
    for (int i = 0; i < 4; ++i) {
        const int f4 = t + 256 * i;       // float4 index in row, 0..1023 (coalesced)
        const float4 v = wrow4[f4];
        const int f    = f4 * 4;          // flat float index
        const int lutc = f >> 6;          // which LUT
        const int e    = f & 63;          // entry 0..60, 4 consecutive share a LUT
        float* dst = &wq[lutc * WSTRIDE + e];
        dst[0] = 0.5f * tanhf(v.x) + 0.5f;
        dst[1] = 0.5f * tanhf(v.y) + 0.5f;
        dst[2] = 0.5f * tanhf(v.z) + 0.5f;
        dst[3] = 0.5f * tanhf(v.w) + 0.5f;
    }
    __syncthreads();

    const int lut = t & 63;          // lane i of each wave handles lut i
    const int g   = t >> 6;          // wave id 0..3 -> 8 (b,r) rows each

    // ---- load this lut's 64-entry table into registers ONCE (reused 8x) ----
    float tab[TBL];
#pragma unroll
    for (int i = 0; i < TBL; ++i) tab[i] = wq[lut * WSTRIDE + i];

    // ---- Phase 2: 8 batch-rows per thread ----
    for (int j = 0; j < 8; ++j) {
        const int br = g * 8 + j;    // 0..31
        // x[br, o, lut*6 .. lut*6+5] — 8B-aligned (lut*6 even); wave reads
        // a contiguous 1536B window -> coalesced.
        const float2* xp = reinterpret_cast<const float2*>(
            x + ((size_t)br * OUT_NUM + o) * (LUT_NUM * LUT_K) + lut * LUT_K);
        const float2 p01 = xp[0];
        const float2 p23 = xp[1];
        const float2 p45 = xp[2];

        // binary-tree soft interpolation, fully unrolled in registers:
        // y = y0 + bit*(y1 - y0)  ==  (1-bit)*y0 + bit*y1
        float y[32];
#pragma unroll
        for (int p = 0; p < 32; ++p)
            y[p] = fmaf(p01.x, tab[2*p+1] - tab[2*p], tab[2*p]);
#pragma unroll
        for (int p = 0; p < 16; ++p)
            y[p] = fmaf(p01.y, y[2*p+1] - y[2*p], y[2*p]);
#pragma unroll
        for (int p = 0; p < 8; ++p)
            y[p] = fmaf(p23.x, y[2*p+1] - y[2*p], y[2*p]);
#pragma unroll
        for (int p = 0; p < 4; ++p)
            y[p] = fmaf(p23.y, y[2*p+1] - y[2*p], y[2*p]);
#pragma unroll
        for (int p = 0; p < 2; ++p)
            y[p] = fmaf(p45.x, y[2*p+1] - y[2*p], y[2*p]);
        const float res = fmaf(p45.y, y[1] - y[0], y[0]);

        // out[br, o, lut] — lanes 0..63 write contiguous 256B
        out[((size_t)br * OUT_NUM + o) * LUT_NUM + lut] = res;
    }
}

extern "C" void kernel_launch(void* const* d_in, const int* in_sizes, int n_in,
                              void* d_out, int out_size, void* d_ws, size_t ws_size,
                              hipStream_t stream)
{
    const float* x   = (const float*)d_in[0];   // [16,2,1024,384] f32
    const float* w   = (const float*)d_in[1];   // [1024,64,64]    f32
    float*       out = (float*)d_out;           // [16,2,1024,64]  f32
    lut_fwd_kernel<<<OUT_NUM, 256, 0, stream>>>(x, w, out);
}

// Round 2
// 96.130 us; speedup vs baseline: 1.0176x; 1.0176x over previous
//
#include <hip/hip_runtime.h>
#include <math.h>

#define OUT_NUM 1024
#define LUT_NUM 64
#define LUT_K   6
#define TBL     64      // 1 << LUT_K
#define WSTRIDE 65      // pad 64 -> 65 floats: bank = (lut + i) % 32, 2-way (free)

// (tanh(v)+1)/2 == sigmoid(2v) = 1/(1+exp(-2v)).
// v_exp_f32 + v_rcp_f32: ~4 VALU ops, rel err ~1e-6 (threshold is 1.8e-2).
__device__ __forceinline__ float softbit(float v) {
    return __builtin_amdgcn_rcpf(1.0f + __expf(-2.0f * v));
}

__global__ __launch_bounds__(256, 2)   // cap 256 VGPRs: tab[64]+px[24]+y[32] must NOT spill
void lut_fwd_kernel(const float* __restrict__ x,
                    const float* __restrict__ w,
                    float* __restrict__ out)
{
    __shared__ float wq[LUT_NUM * WSTRIDE];   // 16.6 KiB

    const int o = blockIdx.x;       // output-feature index, 0..1023
    const int t = threadIdx.x;      // 0..255

    // ---- Phase 1: stage + soft-quantize w[o,:,:] (4096 floats) into LDS ----
    const float4* wrow4 = reinterpret_cast<const float4*>(w + (size_t)o * (LUT_NUM * TBL));
#pragma unroll
    for (int i = 0; i < 4; ++i) {
        const int f4 = t + 256 * i;       // float4 index in row, 0..1023 (coalesced)
        const float4 v = wrow4[f4];
        const int f    = f4 * 4;          // flat float index
        const int lutc = f >> 6;          // which LUT
        const int e    = f & 63;          // entry 0..60, 4 consecutive share a LUT
        float* dst = &wq[lutc * WSTRIDE + e];
        dst[0] = softbit(v.x);
        dst[1] = softbit(v.y);
        dst[2] = softbit(v.z);
        dst[3] = softbit(v.w);
    }
    __syncthreads();

    const int lut = t & 63;          // lane i of each wave handles lut i
    const int g   = t >> 6;          // wave id 0..3 -> 8 (b,r) rows each

    // ---- this lut's 64-entry table into registers ONCE (reused 8x) ----
    float tab[TBL];
#pragma unroll
    for (int i = 0; i < TBL; ++i) tab[i] = wq[lut * WSTRIDE + i];

    // ---- prefetch ALL x for this thread's 8 rows: 24 independent loads ----
    const size_t xlane = (size_t)o * (LUT_NUM * LUT_K) + lut * LUT_K;  // 8B-aligned
    float2 px[8][3];
#pragma unroll
    for (int j = 0; j < 8; ++j) {
        const int br = g * 8 + j;    // 0..31
        const float2* xp = reinterpret_cast<const float2*>(
            x + (size_t)br * (OUT_NUM * LUT_NUM * LUT_K) + xlane);
        px[j][0] = xp[0];
        px[j][1] = xp[1];
        px[j][2] = xp[2];
    }

    // ---- Phase 2: 8 rows of pure-register binary-tree interpolation ----
#pragma unroll
    for (int j = 0; j < 8; ++j) {
        const int br = g * 8 + j;
        const float2 p01 = px[j][0];
        const float2 p23 = px[j][1];
        const float2 p45 = px[j][2];

        float y[32];
#pragma unroll
        for (int p = 0; p < 32; ++p)
            y[p] = fmaf(p01.x, tab[2*p+1] - tab[2*p], tab[2*p]);
#pragma unroll
        for (int p = 0; p < 16; ++p)
            y[p] = fmaf(p01.y, y[2*p+1] - y[2*p], y[2*p]);
#pragma unroll
        for (int p = 0; p < 8; ++p)
            y[p] = fmaf(p23.x, y[2*p+1] - y[2*p], y[2*p]);
#pragma unroll
        for (int p = 0; p < 4; ++p)
            y[p] = fmaf(p23.y, y[2*p+1] - y[2*p], y[2*p]);
#pragma unroll
        for (int p = 0; p < 2; ++p)
            y[p] = fmaf(p45.x, y[2*p+1] - y[2*p], y[2*p]);
        const float res = fmaf(p45.y, y[1] - y[0], y[0]);

        // out[br, o, lut] — lanes 0..63 write contiguous 256B
        out[((size_t)br * OUT_NUM + o) * LUT_NUM + lut] = res;
    }
}

extern "C" void kernel_launch(void* const* d_in, const int* in_sizes, int n_in,
                              void* d_out, int out_size, void* d_ws, size_t ws_size,
                              hipStream_t stream)
{
    const float* x   = (const float*)d_in[0];   // [16,2,1024,384] f32
    const float* w   = (const float*)d_in[1];   // [1024,64,64]    f32
    float*       out = (float*)d_out;           // [16,2,1024,64]  f32
    lut_fwd_kernel<<<OUT_NUM, 256, 0, stream>>>(x, w, out);
}

// Round 3
// 93.611 us; speedup vs baseline: 1.0450x; 1.0269x over previous
//
#include <hip/hip_runtime.h>
#include <math.h>

#define OUT_NUM 1024
#define LUT_NUM 64
#define LUT_K   6
#define TBL     64      // 1 << LUT_K
#define WSTRIDE 65      // 64 data + 1 pad: reg-load bank = (lut + i) % 32, 2-way (free)

// (tanh(v)+1)/2 == sigmoid(2v) = 1/(1+exp(-2v)).  rel err ~1e-6, threshold 1.8e-2.
// exp(-inf)->0 => 1 ; exp(+inf)->inf => rcp -> 0 : saturates correctly.
__device__ __forceinline__ float softbit(float v) {
    return __builtin_amdgcn_rcpf(1.0f + __expf(-2.0f * v));
}

// 128-VGPR budget: evn[32]+dif[32]+y[32]+row x(6)+addr ~= 110 live peak.
// (256,4) => 4 waves/SIMD => 16 waves/CU => 4 blocks/CU => all 1024 blocks
// resident in a single round (no tail).
__global__ __launch_bounds__(256, 4)
void lut_fwd_kernel(const float* __restrict__ x,
                    const float* __restrict__ w,
                    float* __restrict__ out)
{
    __shared__ float wq[LUT_NUM * WSTRIDE];   // per lut: [0..31]=evn, [32..63]=dif

    const int o = blockIdx.x;       // output-feature index, 0..1023
    const int t = threadIdx.x;      // 0..255

    // ---- Phase 1: stage w[o,:,:], quantize, split into (even, odd-even) ----
    const float4* wrow4 = reinterpret_cast<const float4*>(w + (size_t)o * (LUT_NUM * TBL));
#pragma unroll
    for (int i = 0; i < 4; ++i) {
        const int f4 = t + 256 * i;       // float4 index in row, 0..1023 (coalesced)
        const float4 v = wrow4[f4];
        const int f    = f4 * 4;          // flat float index (multiple of 4)
        const int lutc = f >> 6;          // which LUT
        const int p    = (f & 63) >> 1;   // pair index (even)
        const float s0 = softbit(v.x);
        const float s1 = softbit(v.y);
        const float s2 = softbit(v.z);
        const float s3 = softbit(v.w);
        float* row = &wq[lutc * WSTRIDE];
        row[p]          = s0;
        row[32 + p]     = s1 - s0;        // level-0 diff precomputed once
        row[p + 1]      = s2;
        row[33 + p]     = s3 - s2;
    }
    __syncthreads();

    const int lut = t & 63;          // lane i of each wave handles lut i
    const int g   = t >> 6;          // wave id 0..3 -> 8 (b,r) rows each

    // ---- this lut's table into registers ONCE (reused 8x) ----
    const float* row = &wq[lut * WSTRIDE];
    float evn[32], dif[32];
#pragma unroll
    for (int p = 0; p < 32; ++p) { evn[p] = row[p]; dif[p] = row[32 + p]; }

    const float* xb = x + (size_t)o * (LUT_NUM * LUT_K) + lut * LUT_K;   // 8B-aligned
    float* ob = out + (size_t)o * LUT_NUM + lut;

    // ---- Phase 2: 8 rows, strictly sequential (bounded live set) ----
#pragma unroll
    for (int j = 0; j < 8; ++j) {
        const int br = g * 8 + j;    // 0..31
        const float2* xp = reinterpret_cast<const float2*>(xb + (size_t)br * (OUT_NUM * LUT_NUM * LUT_K));
        const float2 p01 = xp[0];
        const float2 p23 = xp[1];
        const float2 p45 = xp[2];

        float y[32];
#pragma unroll
        for (int p = 0; p < 32; ++p)
            y[p] = fmaf(p01.x, dif[p], evn[p]);          // level 0: single fma
#pragma unroll
        for (int p = 0; p < 16; ++p)
            y[p] = fmaf(p01.y, y[2*p+1] - y[2*p], y[2*p]);
#pragma unroll
        for (int p = 0; p < 8; ++p)
            y[p] = fmaf(p23.x, y[2*p+1] - y[2*p], y[2*p]);
#pragma unroll
        for (int p = 0; p < 4; ++p)
            y[p] = fmaf(p23.y, y[2*p+1] - y[2*p], y[2*p]);
#pragma unroll
        for (int p = 0; p < 2; ++p)
            y[p] = fmaf(p45.x, y[2*p+1] - y[2*p], y[2*p]);
        const float res = fmaf(p45.y, y[1] - y[0], y[0]);

        // out[br, o, lut] — lanes 0..63 write contiguous 256B
        ob[(size_t)br * (OUT_NUM * LUT_NUM)] = res;
    }
}

extern "C" void kernel_launch(void* const* d_in, const int* in_sizes, int n_in,
                              void* d_out, int out_size, void* d_ws, size_t ws_size,
                              hipStream_t stream)
{
    const float* x   = (const float*)d_in[0];   // [16,2,1024,384] f32
    const float* w   = (const float*)d_in[1];   // [1024,64,64]    f32
    float*       out = (float*)d_out;           // [16,2,1024,64]  f32
    lut_fwd_kernel<<<OUT_NUM, 256, 0, stream>>>(x, w, out);
}